// Round 7
// baseline (611.302 us; speedup 1.0000x reference)
//
#include <hip/hip_runtime.h>
#include <math.h>
#include <string.h>

#define Nn 4000
#define Dd 256
#define Tt 52
#define Kk 20
#define Pp 100
#define CH 4          // t-chunks for data kernel
#define TC 13         // Tt / CH

// ws layout (float offsets) — every slot read by final is written every launch
#define OFF_W       0        // 5408: [0]=Kinv_lam, [2704]=Kinv_phi (unscaled)
#define OFF_MLAM_P  5408     // 125 * 2704 partial Grams  (end 343408)
#define OFF_MPHI_P  343408   // 20  * 2704 partial Grams  (end 397488)
#define OFF_DLP     397488   // 2000 per-block data-loss partials (end 399488)
#define OFF_EVP     399488   // u8[4000*256] = 256000 float slots (end 655488)
#define OFF_PHIP    655488   // [t][k][d] : 52*20*256 = 266240 floats (end 921728)

#define GR_ROWS 128

// prep role ranges — gram role counts MUST cover 5120 / 80000 rows (R6 bug)
#define RB_KINV0   0     // 2 blocks: device Cholesky-inverse of K+jit*I
#define RB_PHIP0   2     // 52 blocks: sigmoid(phi) transpose
#define RB_GPHI0   54    // 20 blocks: gram of phi deviations (2 tiles each = 5120 rows)
#define RB_GLAM0   74    // 125 blocks: gram of lambda deviations (5 tiles = 80000 rows)
#define RB_EVP0    199   // 128 blocks: ev int32 -> u8
#define RB_TOTAL   327

// ---- device Cholesky-inverse, double internals, y[] in registers ----
__device__ void kinv_block(float ls, double jit, float* __restrict__ outW,
                           double* __restrict__ Ash /* 52*53 */) {
    const int tid = threadIdx.x;
    float ls2 = ls * ls;
    for (int idx = tid; idx < 52 * 52; idx += 256) {
        int i = idx / 52, j = idx - 52 * i;
        int di = i - j;
        float sq = (float)(di * di);
        float arg = (-0.5f * sq) / ls2;               // np float32 arithmetic
        float kf = (float)exp((double)arg);           // ~np.exp to 1 ulp
        float aij = (i == j) ? (float)(1.0 + jit) : kf;
        Ash[i * 53 + j] = (double)aij;
    }
    __syncthreads();
    // in-place lower Cholesky; all 256 threads hit both barriers
    for (int j = 0; j < 52; ++j) {
        if (tid == 0) {
            double s = Ash[j * 53 + j];
            for (int k = 0; k < j; ++k) { double v = Ash[j * 53 + k]; s -= v * v; }
            Ash[j * 53 + j] = sqrt(s);
        }
        __syncthreads();
        if (tid > j && tid < 52) {
            double s = Ash[tid * 53 + j];
            for (int k = 0; k < j; ++k) s -= Ash[tid * 53 + k] * Ash[j * 53 + k];
            Ash[tid * 53 + j] = s / Ash[j * 53 + j];
        }
        __syncthreads();
    }
    // thread c solves K x = e_c with y[] register-resident
    if (tid < 52) {
        const int c = tid;
        double y[52];
        for (int i = 0; i < 52; ++i) {
            double s = (i == c) ? 1.0 : 0.0;
            for (int k = 0; k < i; ++k) s -= Ash[i * 53 + k] * y[k];
            y[i] = s / Ash[i * 53 + i];
        }
        for (int i = 51; i >= 0; --i) {
            double s = y[i];
            for (int k = i + 1; k < 52; ++k) s -= Ash[k * 53 + i] * y[k];
            y[i] = s / Ash[i * 53 + i];
        }
        for (int i = 0; i < 52; ++i) outW[i * 52 + c] = (float)y[i];
    }
}

// ---------------- merged prep kernel ----------------
__global__ __launch_bounds__(256) void prep_kernel(
    const float* __restrict__ lam, const float* __restrict__ phi,
    const float* __restrict__ gamma, const float* __restrict__ G,
    const float* __restrict__ logit_prev, const int* __restrict__ ev,
    float* __restrict__ phip_t, unsigned char* __restrict__ evp,
    float* __restrict__ Mlam_p, float* __restrict__ Mphi_p,
    float* __restrict__ W,
    float ls1, double j1, float ls2, double j2) {
    __shared__ __align__(16) char smem[29184];           // union: Ash / rows+meanv
    double* Ash = (double*)smem;                         // 22048 B
    float (*rows)[56] = (float(*)[56])smem;              // 28672 B
    float* meanv = (float*)(smem + GR_ROWS * 56 * 4);    // 512 B
    const int bx = blockIdx.x, tid = threadIdx.x;

    if (bx < RB_PHIP0) {
        if (bx == 0) kinv_block(ls1, j1, W, Ash);
        else         kinv_block(ls2, j2, W + 2704, Ash);
        return;
    }
    if (bx < RB_GPHI0) {
        // phip_t[t][k][d] = sigmoid(phi[k][d][t]); thread per (d,t)
        int gid = (bx - RB_PHIP0) * 256 + tid;           // d*52 + t
        int d = gid / Tt, t = gid - d * Tt;
        float v[Kk];
#pragma unroll
        for (int k = 0; k < Kk; ++k) {
            float x = phi[k * (Dd * Tt) + gid];
            v[k] = 1.f / (1.f + __expf(-x));
        }
#pragma unroll
        for (int k = 0; k < Kk; ++k)
            phip_t[((size_t)t * Kk + k) * Dd + d] = v[k];
        return;
    }
    if (bx < RB_GLAM0) {
        // partial Gram of (phi - logit_prev); 2 tiles; own output slot
        int slot = bx - RB_GPHI0;                        // 0..19
        int ta = tid % 13, tb = tid / 13;
        float acc[4][4] = {};
        for (int it = 0; it < 2; ++it) {
            int R0 = (slot * 2 + it) * GR_ROWS;
            __syncthreads();
            for (int idx = tid; idx < GR_ROWS * Tt; idx += 256) {
                int r = idx / Tt, t = idx - r * Tt;
                int R = R0 + r;
                rows[r][t] = phi[R * Tt + t] - logit_prev[(R & 255) * Tt + t];
            }
            __syncthreads();
            if (tb < 13) {
                for (int r = 0; r < GR_ROWS; ++r) {
                    float4 a = *(const float4*)&rows[r][4 * ta];
                    float4 b = *(const float4*)&rows[r][4 * tb];
                    float av[4] = {a.x, a.y, a.z, a.w};
                    float bv[4] = {b.x, b.y, b.z, b.w};
#pragma unroll
                    for (int i = 0; i < 4; ++i)
#pragma unroll
                        for (int j = 0; j < 4; ++j) acc[i][j] += av[i] * bv[j];
                }
            }
        }
        if (tb < 13)
#pragma unroll
            for (int i = 0; i < 4; ++i)
#pragma unroll
                for (int j = 0; j < 4; ++j)
                    Mphi_p[slot * 2704 + (4 * ta + i) * Tt + 4 * tb + j] = acc[i][j];
        return;
    }
    if (bx < RB_EVP0) {
        // partial Gram of (lambda - G@gamma); 5 tiles; own output slot
        int slot = bx - RB_GLAM0;                        // 0..124
        int ta = tid % 13, tb = tid / 13;
        float acc[4][4] = {};
        for (int it = 0; it < 5; ++it) {
            int R0 = (slot * 5 + it) * GR_ROWS;
            __syncthreads();
            if (tid < GR_ROWS) {
                int R = R0 + tid;
                int n = R / Kk, k = R - n * Kk;
                float m = 0.f;
                for (int p = 0; p < Pp; ++p) m += G[n * Pp + p] * gamma[p * Kk + k];
                meanv[tid] = m;
            }
            __syncthreads();
            for (int idx = tid; idx < GR_ROWS * Tt; idx += 256) {
                int r = idx / Tt, t = idx - r * Tt;
                int R = R0 + r;
                rows[r][t] = lam[R * Tt + t] - meanv[r];
            }
            __syncthreads();
            if (tb < 13) {
                for (int r = 0; r < GR_ROWS; ++r) {
                    float4 a = *(const float4*)&rows[r][4 * ta];
                    float4 b = *(const float4*)&rows[r][4 * tb];
                    float av[4] = {a.x, a.y, a.z, a.w};
                    float bv[4] = {b.x, b.y, b.z, b.w};
#pragma unroll
                    for (int i = 0; i < 4; ++i)
#pragma unroll
                        for (int j = 0; j < 4; ++j) acc[i][j] += av[i] * bv[j];
                }
            }
        }
        if (tb < 13)
#pragma unroll
            for (int i = 0; i < 4; ++i)
#pragma unroll
                for (int j = 0; j < 4; ++j)
                    Mlam_p[slot * 2704 + (4 * ta + i) * Tt + 4 * tb + j] = acc[i][j];
        return;
    }
    {
        // ev int32 -> u8 pack
        const int4* src = (const int4*)ev;
        unsigned int* dst = (unsigned int*)evp;
        int gtid = (bx - RB_EVP0) * 256 + tid;
        for (int i = gtid; i < (Nn * Dd) / 4; i += 128 * 256) {
            int4 v = src[i];
            dst[i] = (unsigned)v.x | ((unsigned)v.y << 8) |
                     ((unsigned)v.z << 16) | ((unsigned)v.w << 24);
        }
        return;
    }
}

// ---------------- data loss kernel (R4 structure: fused softmax, TC=13) ------
// grid 2000: ng = blockIdx>>2 (8 n's), chunk = blockIdx&3 (13 t's), 256 d-lanes
__global__ __launch_bounds__(256) void data_kernel(const float* __restrict__ lam,
                                                   const float* __restrict__ phip_t,
                                                   const float* __restrict__ Y,
                                                   const unsigned char* __restrict__ evp,
                                                   float* __restrict__ DLp) {
    __shared__ __align__(16) float thS[TC][8][Kk];   // 8.3 KB
    __shared__ float lamS[8][Kk][TC + 1];            // 4.5 KB
    __shared__ float wsum[4];
    const int tid = threadIdx.x;
    const int d = tid;
    const int ng = blockIdx.x >> 2;
    const int t0 = (blockIdx.x & 3) * TC;
    const int n0 = ng * 8;

    // Phase A: stage lambda slice [8 n][20 k][13 t] (chunks partition t)
    if (tid < 8 * Kk) {
        int n = tid / Kk, k = tid - n * Kk;
        const float* src = lam + ((size_t)(n0 + n) * Kk + k) * Tt + t0;
#pragma unroll
        for (int j = 0; j < TC; ++j) lamS[n][k][j] = src[j];
    }
    __syncthreads();
    // Phase B: softmax over k per (n, j)
    if (tid < 8 * TC) {
        int n = tid / TC, j = tid - n * TC;
        float v[Kk];
        float m = -1e30f;
#pragma unroll
        for (int k = 0; k < Kk; ++k) { v[k] = lamS[n][k][j]; m = fmaxf(m, v[k]); }
        float s = 0.f;
#pragma unroll
        for (int k = 0; k < Kk; ++k) { v[k] = __expf(v[k] - m); s += v[k]; }
        float inv = 1.f / s;
#pragma unroll
        for (int k = 0; k < Kk; ++k) thS[j][n][k] = v[k] * inv;
    }

    // per-(n,d) event data; Y-gather only in e-owning chunk, consumed in epilogue
    int e[8];
    float Yv[8], acc[8], pie[8];
#pragma unroll
    for (int g = 0; g < 8; ++g) {
        e[g] = evp[(n0 + g) * Dd + d];               // u8, coalesced
        acc[g] = 0.f;
        pie[g] = 0.5f;
        Yv[g] = 0.f;
        if (e[g] >= t0 && e[g] < t0 + TC)
            Yv[g] = __builtin_nontemporal_load(
                Y + ((size_t)((n0 + g) * Dd + d)) * Tt + e[g]);
    }
    __syncthreads();

    for (int j = 0; j < TC; ++j) {
        int t = t0 + j;
        float pv[Kk];
        const float* pt = phip_t + (size_t)t * (Kk * Dd) + d;
#pragma unroll
        for (int k = 0; k < Kk; ++k) pv[k] = pt[k * Dd];   // coalesced in d
#pragma unroll
        for (int g = 0; g < 8; ++g) {
            const float4* th = (const float4*)&thS[j][g][0];  // LDS broadcast
            float4 a0 = th[0], a1 = th[1], a2 = th[2], a3 = th[3], a4 = th[4];
            float pi = a0.x * pv[0] + a0.y * pv[1] + a0.z * pv[2] + a0.w * pv[3]
                     + a1.x * pv[4] + a1.y * pv[5] + a1.z * pv[6] + a1.w * pv[7]
                     + a2.x * pv[8] + a2.y * pv[9] + a2.z * pv[10] + a2.w * pv[11]
                     + a3.x * pv[12] + a3.y * pv[13] + a3.z * pv[14] + a3.w * pv[15]
                     + a4.x * pv[16] + a4.y * pv[17] + a4.z * pv[18] + a4.w * pv[19];
            pi = fminf(fmaxf(pi, 1e-8f), 1.0f - 1e-8f);
            float lg = __logf(1.f - pi);
            if (t <= e[g]) acc[g] += lg;
            pie[g] = (t == e[g]) ? pi : pie[g];
        }
    }
    float tsum = 0.f;
#pragma unroll
    for (int g = 0; g < 8; ++g)
        tsum += acc[g] + Yv[g] * (__logf(pie[g]) - __logf(1.f - pie[g]));
    for (int off = 32; off; off >>= 1) tsum += __shfl_down(tsum, off, 64);
    if ((tid & 63) == 0) wsum[tid >> 6] = tsum;
    __syncthreads();
    if (tid == 0)
        DLp[blockIdx.x] = -(wsum[0] + wsum[1] + wsum[2] + wsum[3]);   // no atomic
}

// out = sum(DLp)/N + 0.5/N*<Kinv_lam, sum Mlam_p> + 0.5/D*<Kinv_phi, sum Mphi_p>
__global__ __launch_bounds__(1024) void final_kernel(const float* __restrict__ ws,
                                                     float* __restrict__ out) {
    const int tid = threadIdx.x;
    double s = 0.0;
    for (int i = tid; i < 2704; i += 1024) {
        double ml = 0.0, mp = 0.0;
        for (int b = 0; b < 125; ++b) ml += (double)ws[OFF_MLAM_P + b * 2704 + i];
        for (int b = 0; b < 20; ++b)  mp += (double)ws[OFF_MPHI_P + b * 2704 + i];
        s += (double)ws[OFF_W + i] * ml * (0.5 / Nn)
           + (double)ws[OFF_W + 2704 + i] * mp * (0.5 / Dd);
    }
    double dl = 0.0;
    for (int i = tid; i < (Nn / 8) * CH; i += 1024) dl += (double)ws[OFF_DLP + i];
    s += dl / Nn;
    __shared__ double red[1024];
    red[tid] = s;
    __syncthreads();
    for (int off = 512; off; off >>= 1) {
        if (tid < off) red[tid] += red[tid + off];
        __syncthreads();
    }
    if (tid == 0) out[0] = (float)red[0];
}

// ------- host-side jitter search (dlopen-time, CPU only, no HIP calls) -------

static void build_K_f(double ls_in, float Kf[52][52]) {
    float ls = (float)ls_in;
    float ls2 = ls * ls;
    for (int i = 0; i < 52; ++i)
        for (int j = 0; j < 52; ++j) {
            float sq = (float)((i - j) * (i - j));
            float arg = (-0.5f * sq) / ls2;
            Kf[i][j] = expf(arg);
        }
}

static void jacobi_eig(double a[52][52], double ev[52]) {
    const int n = 52;
    for (int sweep = 0; sweep < 100; ++sweep) {
        double off = 0;
        for (int p = 0; p < n - 1; ++p)
            for (int q = p + 1; q < n; ++q) off += a[p][q] * a[p][q];
        if (off < 1e-24) break;
        for (int p = 0; p < n - 1; ++p)
            for (int q = p + 1; q < n; ++q) {
                double apq = a[p][q];
                if (fabs(apq) < 1e-300) continue;
                double th = (a[q][q] - a[p][p]) / (2.0 * apq);
                double t = (th >= 0 ? 1.0 : -1.0) / (fabs(th) + sqrt(th * th + 1.0));
                double c = 1.0 / sqrt(t * t + 1.0), s = t * c;
                for (int i = 0; i < n; ++i) {
                    double aip = a[i][p], aiq = a[i][q];
                    a[i][p] = c * aip - s * aiq;
                    a[i][q] = s * aip + c * aiq;
                }
                for (int i = 0; i < n; ++i) {
                    double api = a[p][i], aqi = a[q][i];
                    a[p][i] = c * api - s * aqi;
                    a[q][i] = s * api + c * aqi;
                }
            }
    }
    for (int i = 0; i < n; ++i) ev[i] = a[i][i];
}

static double cond_of(const float Kf[52][52], double jitter) {
    double A[52][52], ev[52];
    float jf = (float)jitter;
    for (int i = 0; i < 52; ++i)
        for (int j = 0; j < 52; ++j) A[i][j] = (double)Kf[i][j];
    for (int i = 0; i < 52; ++i) A[i][i] = (double)(float)(Kf[i][i] + jf);
    jacobi_eig(A, ev);
    double mx = 0.0, mn = 1e300;
    for (int i = 0; i < 52; ++i) {
        double a = fabs(ev[i]);
        if (a > mx) mx = a;
        if (a < mn) mn = a;
    }
    if (mn <= 0.0) return 1e300;
    return mx / mn;
}

static double find_jitter(const float Kf[52][52]) {
    double jitter = 1e-4;
    while (true) {
        if (cond_of(Kf, jitter) < 1e4) break;
        jitter *= 2.0;
        if (jitter > 0.1) break;
    }
    return jitter;
}

struct JitterInit {
    double j_lam, j_phi;
    JitterInit() {
        float Kf[52][52];
        build_K_f(52.0 / 4.0, Kf);
        j_lam = find_jitter(Kf);
        build_K_f(52.0 / 3.0, Kf);
        j_phi = find_jitter(Kf);
    }
};
static JitterInit g_jit;   // constants; kernel_launch identical every call

// ---------------- launch: 3 kernel nodes, zero memcpy/memset ----------------

extern "C" void kernel_launch(void* const* d_in, const int* in_sizes, int n_in,
                              void* d_out, int out_size, void* d_ws, size_t ws_size,
                              hipStream_t stream) {
    (void)in_sizes; (void)n_in; (void)out_size; (void)ws_size;
    const float* lam        = (const float*)d_in[0];
    const float* phi        = (const float*)d_in[1];
    const float* gamma      = (const float*)d_in[2];
    const float* G          = (const float*)d_in[3];
    const float* Y          = (const float*)d_in[4];
    const float* logit_prev = (const float*)d_in[5];
    const int*   ev         = (const int*)d_in[6];
    float* out = (float*)d_out;
    float* ws  = (float*)d_ws;

    prep_kernel<<<RB_TOTAL, 256, 0, stream>>>(
        lam, phi, gamma, G, logit_prev, ev,
        ws + OFF_PHIP, (unsigned char*)(ws + OFF_EVP),
        ws + OFF_MLAM_P, ws + OFF_MPHI_P, ws + OFF_W,
        (float)(52.0 / 4.0), g_jit.j_lam, (float)(52.0 / 3.0), g_jit.j_phi);
    data_kernel<<<(Nn / 8) * CH, 256, 0, stream>>>(
        lam, ws + OFF_PHIP, Y, (const unsigned char*)(ws + OFF_EVP), ws + OFF_DLP);
    final_kernel<<<1, 1024, 0, stream>>>(ws, out);
}

// Round 8
// 447.746 us; speedup vs baseline: 1.3653x; 1.3653x over previous
//
#include <hip/hip_runtime.h>
#include <math.h>
#include <string.h>

#define Nn 4000
#define Dd 256
#define Tt 52
#define Kk 20
#define Pp 100
#define CH 4          // t-chunks for data kernel
#define TC 13         // Tt / CH

// ws layout (float offsets) — every slot read by final is written every launch
#define OFF_W       0        // 5408: Kinv_lam | Kinv_phi (memcpy'd, pre-scaled)
#define OFF_MLAM_P  5408     // 125 * 2704 partial Grams (end 343408)
#define OFF_MPHI_P  343408   // 20  * 2704 partial Grams (end 397488)
#define OFF_DLP     397488   // 2000 per-block data-loss partials (end 399488)
#define OFF_EVP     399488   // u8[4000*256] = 256000 float slots (end 655488)
#define OFF_PHIP    655488   // [t][k][d] : 266240 floats (end 921728)
#define OFF_THETA   921728   // [t][n][k] : 4160000 floats (end 5081728)

#define GR_ROWS 128

// prep role ranges
#define RB_PHIP0   0      // 52 blocks: sigmoid(phi) transpose
#define RB_THETA0  52     // 813 blocks: softmax -> theta_t
#define RB_GPHI0   865    // 20 blocks: gram of phi deviations (2 tiles = 5120 rows)
#define RB_GLAM0   885    // 125 blocks: gram of lambda deviations (5 tiles = 80000 rows)
#define RB_EVP0    1010   // 128 blocks: ev int32 -> u8
#define RB_TOTAL   1138

// ---------------- merged prep kernel ----------------
__global__ __launch_bounds__(256) void prep_kernel(
    const float* __restrict__ lam, const float* __restrict__ phi,
    const float* __restrict__ gamma, const float* __restrict__ G,
    const float* __restrict__ logit_prev, const int* __restrict__ ev,
    float* __restrict__ theta_t, float* __restrict__ phip_t,
    unsigned char* __restrict__ evp,
    float* __restrict__ Mlam_p, float* __restrict__ Mphi_p) {
    __shared__ float rows[GR_ROWS][56];
    __shared__ float meanv[GR_ROWS];
    const int bx = blockIdx.x, tid = threadIdx.x;

    if (bx < RB_THETA0) {
        // phip_t[t][k][d] = sigmoid(phi[k][d][t]); thread per (d,t)
        int gid = bx * 256 + tid;                    // d*52 + t
        int d = gid / Tt, t = gid - d * Tt;
        float v[Kk];
#pragma unroll
        for (int k = 0; k < Kk; ++k) {
            float x = phi[k * (Dd * Tt) + gid];
            v[k] = 1.f / (1.f + __expf(-x));
        }
#pragma unroll
        for (int k = 0; k < Kk; ++k)
            phip_t[((size_t)t * Kk + k) * Dd + d] = v[k];
        return;
    }
    if (bx < RB_GPHI0) {
        // theta_t[t][n][k] = softmax_k(lambda[n][k][t]); thread per (n,t)
        int gid = (bx - RB_THETA0) * 256 + tid;
        if (gid >= Nn * Tt) return;
        int n = gid / Tt, t = gid - n * Tt;
        const float* base = lam + n * Kk * Tt + t;
        float v[Kk];
        float m = -1e30f;
#pragma unroll
        for (int k = 0; k < Kk; ++k) { v[k] = base[k * Tt]; m = fmaxf(m, v[k]); }
        float s = 0.f;
#pragma unroll
        for (int k = 0; k < Kk; ++k) { v[k] = __expf(v[k] - m); s += v[k]; }
        float inv = 1.f / s;
        float* o = theta_t + ((size_t)t * Nn + n) * Kk;
#pragma unroll
        for (int k = 0; k < Kk; ++k) o[k] = v[k] * inv;
        return;
    }
    if (bx < RB_GLAM0) {
        // partial Gram of (phi - logit_prev); 2 tiles; own output slot
        int slot = bx - RB_GPHI0;                    // 0..19
        int ta = tid % 13, tb = tid / 13;
        float acc[4][4] = {};
        for (int it = 0; it < 2; ++it) {
            int R0 = (slot * 2 + it) * GR_ROWS;
            __syncthreads();
            for (int idx = tid; idx < GR_ROWS * Tt; idx += 256) {
                int r = idx / Tt, t = idx - r * Tt;
                int R = R0 + r;
                rows[r][t] = phi[R * Tt + t] - logit_prev[(R & 255) * Tt + t];
            }
            __syncthreads();
            if (tb < 13) {
                for (int r = 0; r < GR_ROWS; ++r) {
                    float4 a = *(const float4*)&rows[r][4 * ta];
                    float4 b = *(const float4*)&rows[r][4 * tb];
                    float av[4] = {a.x, a.y, a.z, a.w};
                    float bv[4] = {b.x, b.y, b.z, b.w};
#pragma unroll
                    for (int i = 0; i < 4; ++i)
#pragma unroll
                        for (int j = 0; j < 4; ++j) acc[i][j] += av[i] * bv[j];
                }
            }
        }
        if (tb < 13)
#pragma unroll
            for (int i = 0; i < 4; ++i)
#pragma unroll
                for (int j = 0; j < 4; ++j)
                    Mphi_p[slot * 2704 + (4 * ta + i) * Tt + 4 * tb + j] = acc[i][j];
        return;
    }
    if (bx < RB_EVP0) {
        // partial Gram of (lambda - G@gamma); 5 tiles; own output slot
        int slot = bx - RB_GLAM0;                    // 0..124
        int ta = tid % 13, tb = tid / 13;
        float acc[4][4] = {};
        for (int it = 0; it < 5; ++it) {
            int R0 = (slot * 5 + it) * GR_ROWS;
            __syncthreads();
            if (tid < GR_ROWS) {
                int R = R0 + tid;
                int n = R / Kk, k = R - n * Kk;
                float m = 0.f;
                for (int p = 0; p < Pp; ++p) m += G[n * Pp + p] * gamma[p * Kk + k];
                meanv[tid] = m;
            }
            __syncthreads();
            for (int idx = tid; idx < GR_ROWS * Tt; idx += 256) {
                int r = idx / Tt, t = idx - r * Tt;
                int R = R0 + r;
                rows[r][t] = lam[R * Tt + t] - meanv[r];
            }
            __syncthreads();
            if (tb < 13) {
                for (int r = 0; r < GR_ROWS; ++r) {
                    float4 a = *(const float4*)&rows[r][4 * ta];
                    float4 b = *(const float4*)&rows[r][4 * tb];
                    float av[4] = {a.x, a.y, a.z, a.w};
                    float bv[4] = {b.x, b.y, b.z, b.w};
#pragma unroll
                    for (int i = 0; i < 4; ++i)
#pragma unroll
                        for (int j = 0; j < 4; ++j) acc[i][j] += av[i] * bv[j];
                }
            }
        }
        if (tb < 13)
#pragma unroll
            for (int i = 0; i < 4; ++i)
#pragma unroll
                for (int j = 0; j < 4; ++j)
                    Mlam_p[slot * 2704 + (4 * ta + i) * Tt + 4 * tb + j] = acc[i][j];
        return;
    }
    {
        // ev int32 -> u8 pack
        const int4* src = (const int4*)ev;
        unsigned int* dst = (unsigned int*)evp;
        int gtid = (bx - RB_EVP0) * 256 + tid;
        for (int i = gtid; i < (Nn * Dd) / 4; i += 128 * 256) {
            int4 v = src[i];
            dst[i] = (unsigned)v.x | ((unsigned)v.y << 8) |
                     ((unsigned)v.z << 16) | ((unsigned)v.w << 24);
        }
        return;
    }
}

// ---------------- data loss kernel ----------------
// grid 2000: ng = blockIdx>>2 (8 n's), chunk = blockIdx&3 (13 t's), 256 d-lanes.
// theta reads are wave-uniform -> scalar-pipe s_load; log-of-product-of-4.
__global__ __launch_bounds__(256) void data_kernel(const float* __restrict__ theta_t,
                                                   const float* __restrict__ phip_t,
                                                   const float* __restrict__ Y,
                                                   const unsigned char* __restrict__ evp,
                                                   float* __restrict__ DLp) {
    __shared__ float wsum[4];
    const int tid = threadIdx.x;
    const int d = tid;
    const int ng = blockIdx.x >> 2;
    const int t0 = (blockIdx.x & 3) * TC;
    const int n0 = ng * 8;

    int e[8];
    float Yv[8], acc[8], pie[8], prod[8];
#pragma unroll
    for (int g = 0; g < 8; ++g) {
        e[g] = evp[(n0 + g) * Dd + d];               // u8, coalesced
        acc[g] = 0.f;
        prod[g] = 1.f;
        pie[g] = 0.5f;
        Yv[g] = 0.f;
        if (e[g] >= t0 && e[g] < t0 + TC)            // only e-owning chunk gathers Y
            Yv[g] = __builtin_nontemporal_load(
                Y + ((size_t)((n0 + g) * Dd + d)) * Tt + e[g]);
    }

    for (int j = 0; j < TC; ++j) {
        int t = t0 + j;
        float pv[Kk];
        const float* pt = phip_t + (size_t)t * (Kk * Dd) + d;
#pragma unroll
        for (int k = 0; k < Kk; ++k) pv[k] = pt[k * Dd];   // coalesced, L2-hot
#pragma unroll
        for (int g = 0; g < 8; ++g) {
            // uniform address (no lane dependence) -> scalar loads
            const float4* th = (const float4*)(theta_t + ((size_t)t * Nn + n0 + g) * Kk);
            float4 a0 = th[0], a1 = th[1], a2 = th[2], a3 = th[3], a4 = th[4];
            float pi = a0.x * pv[0] + a0.y * pv[1] + a0.z * pv[2] + a0.w * pv[3]
                     + a1.x * pv[4] + a1.y * pv[5] + a1.z * pv[6] + a1.w * pv[7]
                     + a2.x * pv[8] + a2.y * pv[9] + a2.z * pv[10] + a2.w * pv[11]
                     + a3.x * pv[12] + a3.y * pv[13] + a3.z * pv[14] + a3.w * pv[15]
                     + a4.x * pv[16] + a4.y * pv[17] + a4.z * pv[18] + a4.w * pv[19];
            pi = fminf(fmaxf(pi, 1e-8f), 1.0f - 1e-8f);
            prod[g] *= (t <= e[g]) ? (1.f - pi) : 1.f;     // >= 1e-32 per 4-group
            pie[g] = (t == e[g]) ? pi : pie[g];
        }
        if ((j & 3) == 3 || j == TC - 1) {
#pragma unroll
            for (int g = 0; g < 8; ++g) { acc[g] += __logf(prod[g]); prod[g] = 1.f; }
        }
    }
    float tsum = 0.f;
#pragma unroll
    for (int g = 0; g < 8; ++g)
        tsum += acc[g] + Yv[g] * (__logf(pie[g]) - __logf(1.f - pie[g]));
    for (int off = 32; off; off >>= 1) tsum += __shfl_down(tsum, off, 64);
    if ((tid & 63) == 0) wsum[tid >> 6] = tsum;
    __syncthreads();
    if (tid == 0)
        DLp[blockIdx.x] = -(wsum[0] + wsum[1] + wsum[2] + wsum[3]);
}

// out = sum(DLp)/N + <W_lam, sum Mlam_p> + <W_phi, sum Mphi_p>  (W pre-scaled)
__global__ __launch_bounds__(1024) void final_kernel(const float* __restrict__ ws,
                                                     float* __restrict__ out) {
    const int tid = threadIdx.x;
    double s = 0.0;
    for (int i = tid; i < 2704; i += 1024) {
        double ml = 0.0, mp = 0.0;
        for (int b = 0; b < 125; ++b) ml += (double)ws[OFF_MLAM_P + b * 2704 + i];
        for (int b = 0; b < 20; ++b)  mp += (double)ws[OFF_MPHI_P + b * 2704 + i];
        s += (double)ws[OFF_W + i] * ml + (double)ws[OFF_W + 2704 + i] * mp;
    }
    double dl = 0.0;
    for (int i = tid; i < (Nn / 8) * CH; i += 1024) dl += (double)ws[OFF_DLP + i];
    s += dl / Nn;
    __shared__ double red[1024];
    red[tid] = s;
    __syncthreads();
    for (int off = 512; off; off >>= 1) {
        if (tid < off) red[tid] += red[tid + off];
        __syncthreads();
    }
    if (tid == 0) out[0] = (float)red[0];
}

// ------- host-side constant math (runs ONCE at dlopen, never inside launch) -------

static void build_K_f(double ls_in, float Kf[52][52]) {
    float ls = (float)ls_in;
    float ls2 = ls * ls;
    for (int i = 0; i < 52; ++i)
        for (int j = 0; j < 52; ++j) {
            float sq = (float)((i - j) * (i - j));
            float arg = (-0.5f * sq) / ls2;
            Kf[i][j] = expf(arg);
        }
}

static void jacobi_eig(double a[52][52], double ev[52]) {
    const int n = 52;
    for (int sweep = 0; sweep < 100; ++sweep) {
        double off = 0;
        for (int p = 0; p < n - 1; ++p)
            for (int q = p + 1; q < n; ++q) off += a[p][q] * a[p][q];
        if (off < 1e-24) break;
        for (int p = 0; p < n - 1; ++p)
            for (int q = p + 1; q < n; ++q) {
                double apq = a[p][q];
                if (fabs(apq) < 1e-300) continue;
                double th = (a[q][q] - a[p][p]) / (2.0 * apq);
                double t = (th >= 0 ? 1.0 : -1.0) / (fabs(th) + sqrt(th * th + 1.0));
                double c = 1.0 / sqrt(t * t + 1.0), s = t * c;
                for (int i = 0; i < n; ++i) {
                    double aip = a[i][p], aiq = a[i][q];
                    a[i][p] = c * aip - s * aiq;
                    a[i][q] = s * aip + c * aiq;
                }
                for (int i = 0; i < n; ++i) {
                    double api = a[p][i], aqi = a[q][i];
                    a[p][i] = c * api - s * aqi;
                    a[q][i] = s * api + c * aqi;
                }
            }
    }
    for (int i = 0; i < n; ++i) ev[i] = a[i][i];
}

static void build_A(const float Kf[52][52], double jitter, double A[52][52]) {
    float jf = (float)jitter;
    for (int i = 0; i < 52; ++i)
        for (int j = 0; j < 52; ++j) A[i][j] = (double)Kf[i][j];
    for (int i = 0; i < 52; ++i) A[i][i] = (double)(float)(Kf[i][i] + jf);
}

static double cond_of(const float Kf[52][52], double jitter) {
    double A[52][52], ev[52];
    build_A(Kf, jitter, A);
    jacobi_eig(A, ev);
    double mx = 0.0, mn = 1e300;
    for (int i = 0; i < 52; ++i) {
        double a = fabs(ev[i]);
        if (a > mx) mx = a;
        if (a < mn) mn = a;
    }
    if (mn <= 0.0) return 1e300;
    return mx / mn;
}

static double find_jitter(const float Kf[52][52]) {
    double jitter = 1e-4;
    while (true) {
        if (cond_of(Kf, jitter) < 1e4) break;
        jitter *= 2.0;
        if (jitter > 0.1) break;
    }
    return jitter;
}

static void chol_inv_scaled(const float Kf[52][52], double jitter, double scale,
                            float* out) {
    const int n = 52;
    double A[52][52], L[52][52];
    build_A(Kf, jitter, A);
    memset(L, 0, sizeof(L));
    for (int j = 0; j < n; ++j) {
        double s = A[j][j];
        for (int k = 0; k < j; ++k) s -= L[j][k] * L[j][k];
        L[j][j] = sqrt(s);
        for (int i = j + 1; i < n; ++i) {
            double v = A[i][j];
            for (int k = 0; k < j; ++k) v -= L[i][k] * L[j][k];
            L[i][j] = v / L[j][j];
        }
    }
    for (int c = 0; c < n; ++c) {
        double y[52], x[52];
        for (int i = 0; i < n; ++i) {
            double v = (i == c) ? 1.0 : 0.0;
            for (int k = 0; k < i; ++k) v -= L[i][k] * y[k];
            y[i] = v / L[i][i];
        }
        for (int i = n - 1; i >= 0; --i) {
            double v = y[i];
            for (int k = i + 1; k < n; ++k) v -= L[k][i] * x[k];
            x[i] = v / L[i][i];
        }
        for (int i = 0; i < n; ++i) out[i * 52 + c] = (float)(x[i] * scale);
    }
}

struct KinvInit {
    float* w;   // PINNED: [0:2704) Kinv_lam*0.5/N, [2704:5408) Kinv_phi*0.5/D
    KinvInit() {
        if (hipHostMalloc((void**)&w, 5408 * sizeof(float)) != hipSuccess)
            w = (float*)malloc(5408 * sizeof(float));
        float Kf[52][52];
        build_K_f(52.0 / 4.0, Kf);
        chol_inv_scaled(Kf, find_jitter(Kf), 0.5 / Nn, w);
        build_K_f(52.0 / 3.0, Kf);
        chol_inv_scaled(Kf, find_jitter(Kf), 0.5 / Dd, w + 2704);
    }
};
static KinvInit g_kinv;   // dlopen-time; kernel_launch identical every call

// ---------------- launch: memcpy + 3 kernels, no memset ----------------

extern "C" void kernel_launch(void* const* d_in, const int* in_sizes, int n_in,
                              void* d_out, int out_size, void* d_ws, size_t ws_size,
                              hipStream_t stream) {
    (void)in_sizes; (void)n_in; (void)out_size; (void)ws_size;
    const float* lam        = (const float*)d_in[0];
    const float* phi        = (const float*)d_in[1];
    const float* gamma      = (const float*)d_in[2];
    const float* G          = (const float*)d_in[3];
    const float* Y          = (const float*)d_in[4];
    const float* logit_prev = (const float*)d_in[5];
    const int*   ev         = (const int*)d_in[6];
    float* out = (float*)d_out;
    float* ws  = (float*)d_ws;

    hipMemcpyAsync(ws + OFF_W, g_kinv.w, 5408 * sizeof(float),
                   hipMemcpyHostToDevice, stream);

    prep_kernel<<<RB_TOTAL, 256, 0, stream>>>(
        lam, phi, gamma, G, logit_prev, ev,
        ws + OFF_THETA, ws + OFF_PHIP, (unsigned char*)(ws + OFF_EVP),
        ws + OFF_MLAM_P, ws + OFF_MPHI_P);
    data_kernel<<<(Nn / 8) * CH, 256, 0, stream>>>(
        ws + OFF_THETA, ws + OFF_PHIP, Y, (const unsigned char*)(ws + OFF_EVP),
        ws + OFF_DLP);
    final_kernel<<<1, 1024, 0, stream>>>(ws, out);
}